// Round 12
// baseline (249.721 us; speedup 1.0000x reference)
//
#include <hip/hip_runtime.h>
#include <hip/hip_bf16.h>
#include <stdint.h>

#define T_TOK 2048
#define HD    1024
#define ID    4096
#define NE    8
#define NN2   8192   // 2*ID
#define CHUNK 256    // T_TOK / NE

typedef short          bf16x8 __attribute__((ext_vector_type(8)));
typedef float          f32x4  __attribute__((ext_vector_type(4)));
typedef unsigned short u16;

__device__ __forceinline__ u16 f2bf(float f) {
    return __builtin_bit_cast(u16, __float2bfloat16(f));
}

// Barrier that does NOT drain vmcnt: LDS-ordering only (T3/T4 pattern).
__device__ __forceinline__ void lgkm_bar() {
    asm volatile("s_waitcnt lgkmcnt(0)" ::: "memory");
    __builtin_amdgcn_s_barrier();
}

// ---------------------------------------------------------------- router ----
__global__ __launch_bounds__(256) void k_router(
    const float* __restrict__ x, const float* __restrict__ rw,
    float* __restrict__ scoresT, u16* __restrict__ xbf, u16* __restrict__ xsbf)
{
    const int t   = blockIdx.x;
    const int tid = threadIdx.x;
    __shared__ float wred[NE][4];
    __shared__ float ssc;

    float4 xv = reinterpret_cast<const float4*>(x + (size_t)t * HD)[tid];
    float p[NE];
#pragma unroll
    for (int e = 0; e < NE; ++e) p[e] = 0.f;
    const float* wrow = rw + (size_t)tid * 4 * NE;
    float xj[4] = {xv.x, xv.y, xv.z, xv.w};
#pragma unroll
    for (int j = 0; j < 4; ++j)
#pragma unroll
        for (int e = 0; e < NE; ++e) p[e] += xj[j] * wrow[j * NE + e];

#pragma unroll
    for (int e = 0; e < NE; ++e) {
        float v = p[e];
#pragma unroll
        for (int o = 32; o > 0; o >>= 1) v += __shfl_down(v, o, 64);
        if ((tid & 63) == 0) wred[e][tid >> 6] = v;
    }
    __syncthreads();
    if (tid == 0) {
        float mx = -3.4e38f; int am = 0;
        float lg[NE];
#pragma unroll
        for (int e = 0; e < NE; ++e) {
            lg[e] = wred[e][0] + wred[e][1] + wred[e][2] + wred[e][3];
            if (lg[e] > mx) { mx = lg[e]; am = e; }
        }
        float sc = 1.f / (1.f + __expf(-mx));
        ssc = sc;
#pragma unroll
        for (int e = 0; e < NE; ++e)
            scoresT[(size_t)e * T_TOK + t] = (e == am) ? sc : 0.f;
    }
    __syncthreads();
    const float sc = ssc;
    ushort4 a, b;
    a.x = f2bf(xj[0]); a.y = f2bf(xj[1]); a.z = f2bf(xj[2]); a.w = f2bf(xj[3]);
    b.x = f2bf(xj[0] * sc); b.y = f2bf(xj[1] * sc); b.z = f2bf(xj[2] * sc); b.w = f2bf(xj[3] * sc);
    reinterpret_cast<ushort4*>(xbf  + (size_t)t * HD)[tid] = a;
    reinterpret_cast<ushort4*>(xsbf + (size_t)t * HD)[tid] = b;
}

// ------------------------------------------------------------------- G1 -----
// Round-12 delta: BK 32->64 (NS 32->16) to amortize the fixed per-step cost.
// BM=256, BN=128, 8 waves (4x2), wave 64x64. A direct from global (dual-bank
// depth-1 prefetch), B fp32 reg-staged DEPTH-1 single bank (reg budget) into
// dbuf LDS with the G2-proven BK=64 swizzle, NON-TEMPORAL B loads,
// lgkm-only barriers. Everything else as r10.
__global__ __launch_bounds__(512, 2) void k_gemm1(
    const u16* __restrict__ xbf, const u16* __restrict__ xsbf,
    const float* __restrict__ sgw, const float* __restrict__ suw,
    const float* __restrict__ gup, u16* __restrict__ h2)
{
    constexpr int BM = 256, BN = 128, BK = 64, NS = HD / BK;   // 16 steps
    const int d = blockIdx.x;
    int mt, nt;
    if (d < 256) { const int r = d & 7, q = d >> 3; nt = r + 8 * (q & 3); mt = q >> 2; }
    else         { const int e = d - 256;           mt = e & 7; nt = 32 + (e >> 3); }
    const int m0 = mt * BM, n0 = nt * BN;

    const u16* A; const float* Bg; const float* Bu; int ldb;
    if (n0 < ID) { A = xbf; Bg = sgw + n0; Bu = suw + n0; ldb = ID; }
    else {
        A = xsbf;
        Bg = gup + (size_t)mt * HD * NN2 + (n0 - ID);
        Bu = Bg + ID;
        ldb = NN2;
    }

    __shared__ u16 Bgs[2][BN * BK];   // 16 KB each buf
    __shared__ u16 Bus[2][BN * BK];

    const int tid  = threadIdx.x;
    const int lane = tid & 63, wid = tid >> 6;
    const int wr = wid >> 1, wc = wid & 1;        // 4 x 2 wave grid
    const int lrow = lane & 15, kg = lane >> 4;

    f32x4 accg[4][4], accu[4][4];
#pragma unroll
    for (int i = 0; i < 4; ++i)
#pragma unroll
        for (int j = 0; j < 4; ++j)
#pragma unroll
            for (int r = 0; r < 4; ++r) { accg[i][j][r] = 0.f; accu[i][j][r] = 0.f; }

    // B staging: 128 cols x 4 k-16-groups; each thread 16 k per matrix.
    const int scol = tid & 127, sgrp = tid >> 7;  // sgrp in {0..3}
    const int ssw  = scol & 7;
    const u16* aBase = A + (size_t)(m0 + wr * 64 + lrow) * HD + kg * 8;

    float rg[16], ru[16];                          // single staging bank
    bf16x8 aF0[8], aF1[8];                         // dual A banks [mf*2+kk]

#define LOADB(ks) do {                                                          \
        const float* bgp_ = Bg + (size_t)((ks) * BK + sgrp * 16) * ldb + scol;  \
        const float* bup_ = Bu + (size_t)((ks) * BK + sgrp * 16) * ldb + scol;  \
        _Pragma("unroll")                                                       \
        for (int j = 0; j < 16; ++j) {                                          \
            rg[j] = __builtin_nontemporal_load(bgp_ + (size_t)j * ldb);         \
            ru[j] = __builtin_nontemporal_load(bup_ + (size_t)j * ldb);         \
        }                                                                       \
    } while (0)

#define STOREB(b) do {                                                          \
        bf16x8 wg0_, wg1_, wu0_, wu1_;                                          \
        _Pragma("unroll")                                                       \
        for (int j = 0; j < 8; ++j) {                                           \
            wg0_[j] = (short)f2bf(rg[j]);     wg1_[j] = (short)f2bf(rg[8 + j]); \
            wu0_[j] = (short)f2bf(ru[j]);     wu1_[j] = (short)f2bf(ru[8 + j]); \
        }                                                                       \
        char* gs_ = (char*)Bgs[b]; char* us_ = (char*)Bus[b];                   \
        *reinterpret_cast<bf16x8*>(gs_ + scol * 128 + (((sgrp * 2 + 0) ^ ssw) * 16)) = wg0_; \
        *reinterpret_cast<bf16x8*>(gs_ + scol * 128 + (((sgrp * 2 + 1) ^ ssw) * 16)) = wg1_; \
        *reinterpret_cast<bf16x8*>(us_ + scol * 128 + (((sgrp * 2 + 0) ^ ssw) * 16)) = wu0_; \
        *reinterpret_cast<bf16x8*>(us_ + scol * 128 + (((sgrp * 2 + 1) ^ ssw) * 16)) = wu1_; \
    } while (0)

#define LOADA(ks, F) do {                                                       \
        _Pragma("unroll")                                                       \
        for (int mf = 0; mf < 4; ++mf)                                          \
            _Pragma("unroll")                                                   \
            for (int kk = 0; kk < 2; ++kk)                                      \
                F[mf * 2 + kk] = *reinterpret_cast<const bf16x8*>(              \
                    aBase + (size_t)mf * 16 * HD + (ks) * BK + kk * 32);        \
    } while (0)

#define MFMAPH(b, F) do {                                                       \
        const char* gs_ = (const char*)Bgs[b];                                  \
        const char* us_ = (const char*)Bus[b];                                  \
        _Pragma("unroll")                                                       \
        for (int kk = 0; kk < 2; ++kk) {                                        \
            bf16x8 bgf_[4], buf_[4];                                            \
            _Pragma("unroll")                                                   \
            for (int nf = 0; nf < 4; ++nf) {                                    \
                const int col_ = wc * 64 + nf * 16 + lrow;                      \
                const int so_  = col_ * 128 + (((kk * 4 + kg) ^ (col_ & 7)) * 16); \
                bgf_[nf] = *reinterpret_cast<const bf16x8*>(gs_ + so_);         \
                buf_[nf] = *reinterpret_cast<const bf16x8*>(us_ + so_);         \
            }                                                                   \
            _Pragma("unroll")                                                   \
            for (int mf = 0; mf < 4; ++mf)                                      \
                _Pragma("unroll")                                               \
                for (int nf = 0; nf < 4; ++nf) {                                \
                    accg[mf][nf] = __builtin_amdgcn_mfma_f32_16x16x32_bf16(     \
                        F[mf * 2 + kk], bgf_[nf], accg[mf][nf], 0, 0, 0);       \
                    accu[mf][nf] = __builtin_amdgcn_mfma_f32_16x16x32_bf16(     \
                        F[mf * 2 + kk], buf_[nf], accu[mf][nf], 0, 0, 0);       \
                }                                                               \
        }                                                                       \
    } while (0)

    // prologue: tile 0 staged, A bank 0 loaded
    LOADB(0);
    LOADA(0, aF0);
    STOREB(0);
    lgkm_bar();

    for (int j = 0; j < NS / 2; ++j) {
        const int ks = 2 * j;
        // even: compute tile ks (buf0, aF0); prefetch ks+1
        {
            const int ka = (ks + 1 < NS) ? ks + 1 : NS - 1;
            LOADB(ka);
            LOADA(ka, aF1);
        }
        MFMAPH(0, aF0);
        STOREB(1);                         // tile ks+1 -> buf1
        lgkm_bar();
        // odd: compute tile ks+1 (buf1, aF1); prefetch ks+2
        {
            const int kb = (ks + 2 < NS) ? ks + 2 : NS - 1;
            LOADB(kb);
            LOADA(kb, aF0);
        }
        MFMAPH(1, aF1);
        STOREB(0);                         // tile ks+2 -> buf0
        lgkm_bar();
    }
#undef LOADB
#undef STOREB
#undef LOADA
#undef MFMAPH

    // SwiGLU epilogue -> bf16 H2
#pragma unroll
    for (int mf = 0; mf < 4; ++mf)
#pragma unroll
        for (int nf = 0; nf < 4; ++nf) {
            const int col = n0 + wc * 64 + nf * 16 + lrow;
#pragma unroll
            for (int r = 0; r < 4; ++r) {
                const int row = m0 + wr * 64 + mf * 16 + kg * 4 + r;
                const float g = accg[mf][nf][r];
                const float u = accu[mf][nf][r];
                const float h = (g / (1.f + __expf(-g))) * u;
                h2[(size_t)row * NN2 + col] = f2bf(h);
            }
        }
}

// ------------------------------------------------------------------- G2 -----
// UNCHANGED round-11 configuration (~92 us): BM=256, BN=64, K split across
// blocks (kh=0 sdw / kh=1 dwn[mt]); mt = XCD (h2 slab L2-hot); 2 wavesets x
// 4 waves over K-quarters; depth-2 B, dual-bank A, lgkm barriers; LDS
// waveset-reduce; kh-partials atomicAdd'ed onto zeroed out.
__global__ __launch_bounds__(512, 1) void k_gemm2(
    const u16* __restrict__ h2, const float* __restrict__ sdw,
    const float* __restrict__ dwn, float* __restrict__ out)
{
    constexpr int BM = 256, BN = 64, BK = 64, NS = 2048 / BK;  // 32 steps/waveset
    const int d   = blockIdx.x;               // 256 blocks
    const int mt  = d & 7;                    // = XCD
    const int q   = d >> 3;
    const int kh  = q & 1;                    // K-half: 0=sdw, 1=dwn[mt]
    const int nt  = q >> 1;                   // 0..15
    const int m0 = mt * BM, n0 = nt * BN;

    const int tid = threadIdx.x;
    const int ws  = tid >> 8;                 // waveset 0/1
    const int wt  = tid & 255;
    const int lane = wt & 63, wid4 = wt >> 6;
    const int wr = wid4;                      // 4x1 wave grid
    const int lrow = lane & 15, kg = lane >> 4;

    __shared__ char smem[65536];
    u16*   BsBase = (u16*)smem;
    float* red    = (float*)smem;

    f32x4 acc[4][4];
#pragma unroll
    for (int i = 0; i < 4; ++i)
#pragma unroll
        for (int j = 0; j < 4; ++j)
#pragma unroll
            for (int r = 0; r < 4; ++r) acc[i][j][r] = 0.f;

    const float* Bbase = kh ? (dwn + (size_t)mt * ID * HD + (size_t)(ws * 2048) * HD)
                            : (sdw + (size_t)(ws * 2048) * HD);
    const u16* aBase = h2 + (size_t)(m0 + wr * 64 + lrow) * NN2
                          + (size_t)kh * ID + (size_t)ws * 2048 + kg * 8;

    const int bcol = wt & 63, bkq = wt >> 6;
    const int bsw  = bcol & 7;

    float rb0[16], rb1[16];
    bf16x8 aF0[8], aF1[8];

#define LOADB2(ks, rb) do {                                                     \
        const float* bb_ = Bbase + (size_t)((ks) * BK + bkq * 16) * HD + n0 + bcol; \
        _Pragma("unroll")                                                       \
        for (int j = 0; j < 16; ++j) rb[j] = bb_[(size_t)j * HD];               \
    } while (0)

#define STOREB2(b, rb) do {                                                     \
        bf16x8 w0_, w1_;                                                        \
        _Pragma("unroll")                                                       \
        for (int j = 0; j < 8; ++j) { w0_[j] = (short)f2bf(rb[j]);              \
                                      w1_[j] = (short)f2bf(rb[8 + j]); }        \
        char* bs_ = (char*)(BsBase + (size_t)(ws * 2 + (b)) * BN * BK);         \
        *reinterpret_cast<bf16x8*>(bs_ + bcol * 128 + (((bkq * 2 + 0) ^ bsw) * 16)) = w0_; \
        *reinterpret_cast<bf16x8*>(bs_ + bcol * 128 + (((bkq * 2 + 1) ^ bsw) * 16)) = w1_; \
    } while (0)

#define LOADA2(ks, F) do {                                                      \
        _Pragma("unroll")                                                       \
        for (int mf = 0; mf < 4; ++mf)                                          \
            _Pragma("unroll")                                                   \
            for (int kk = 0; kk < 2; ++kk)                                      \
                F[mf * 2 + kk] = *reinterpret_cast<const bf16x8*>(              \
                    aBase + (size_t)mf * 16 * NN2 + (ks) * BK + kk * 32);       \
    } while (0)

#define MFMAPH2(b, F) do {                                                      \
        const char* bs_ = (const char*)(BsBase + (size_t)(ws * 2 + (b)) * BN * BK); \
        _Pragma("unroll")                                                       \
        for (int kk = 0; kk < 2; ++kk) {                                        \
            bf16x8 bf_[4];                                                      \
            _Pragma("unroll")                                                   \
            for (int nf = 0; nf < 4; ++nf) {                                    \
                const int col_ = nf * 16 + lrow;                                \
                bf_[nf] = *reinterpret_cast<const bf16x8*>(                     \
                    bs_ + col_ * 128 + (((kk * 4 + kg) ^ (col_ & 7)) * 16));    \
            }                                                                   \
            _Pragma("unroll")                                                   \
            for (int mf = 0; mf < 4; ++mf)                                      \
                _Pragma("unroll")                                               \
                for (int nf = 0; nf < 4; ++nf)                                  \
                    acc[mf][nf] = __builtin_amdgcn_mfma_f32_16x16x32_bf16(      \
                        F[mf * 2 + kk], bf_[nf], acc[mf][nf], 0, 0, 0);         \
        }                                                                       \
    } while (0)

    // prologue
    LOADB2(0, rb0);
    LOADB2(1, rb1);
    LOADA2(0, aF0);
    STOREB2(0, rb0);
    lgkm_bar();

    for (int j = 0; j < NS / 2; ++j) {
        const int ks = 2 * j;
        {
            const int ka = (ks + 1 < NS) ? ks + 1 : NS - 1;
            const int kb = (ks + 2 < NS) ? ks + 2 : NS - 1;
            LOADA2(ka, aF1);
            LOADB2(kb, rb0);
        }
        MFMAPH2(0, aF0);
        STOREB2(1, rb1);
        lgkm_bar();
        {
            const int ka = (ks + 2 < NS) ? ks + 2 : NS - 1;
            const int kb = (ks + 3 < NS) ? ks + 3 : NS - 1;
            LOADA2(ka, aF0);
            LOADB2(kb, rb1);
        }
        MFMAPH2(1, aF1);
        STOREB2(0, rb0);
        lgkm_bar();
    }
#undef LOADB2
#undef STOREB2
#undef LOADA2
#undef MFMAPH2

    // waveset reduce + atomic kh-combine
    lgkm_bar();
    if (ws == 1) {
#pragma unroll
        for (int mf = 0; mf < 4; ++mf)
#pragma unroll
            for (int nf = 0; nf < 4; ++nf)
#pragma unroll
                for (int r = 0; r < 4; ++r) {
                    const int row = wr * 64 + mf * 16 + kg * 4 + r;
                    const int col = nf * 16 + lrow;
                    red[row * 64 + col] = acc[mf][nf][r];
                }
    }
    lgkm_bar();
    if (ws == 0) {
#pragma unroll
        for (int mf = 0; mf < 4; ++mf)
#pragma unroll
            for (int nf = 0; nf < 4; ++nf)
#pragma unroll
                for (int r = 0; r < 4; ++r) {
                    const int row = wr * 64 + mf * 16 + kg * 4 + r;
                    const int col = nf * 16 + lrow;
                    atomicAdd(&out[(size_t)(m0 + row) * HD + n0 + col],
                              acc[mf][nf][r] + red[row * 64 + col]);
                }
    }
}

// --------------------------------------------------------------- launch -----
extern "C" void kernel_launch(void* const* d_in, const int* in_sizes, int n_in,
                              void* d_out, int out_size, void* d_ws, size_t ws_size,
                              hipStream_t stream) {
    const float* x   = (const float*)d_in[0];
    const float* rw  = (const float*)d_in[1];
    const float* gup = (const float*)d_in[2];
    const float* dwn = (const float*)d_in[3];
    const float* sgw = (const float*)d_in[4];
    const float* suw = (const float*)d_in[5];
    const float* sdw = (const float*)d_in[6];

    float* out     = (float*)d_out;
    float* scoresT = out + (size_t)T_TOK * HD;

    char* ws   = (char*)d_ws;
    u16* xbf   = (u16*)ws;                                    // 4 MB
    u16* xsbf  = (u16*)(ws + (size_t)T_TOK * HD * 2);         // 4 MB
    u16* h2    = (u16*)(ws + (size_t)2 * T_TOK * HD * 2);     // 32 MB

    // zero the final-output region: G2 accumulates kh-partials atomically
    hipMemsetAsync(out, 0, (size_t)T_TOK * HD * sizeof(float), stream);

    k_router<<<T_TOK, 256, 0, stream>>>(x, rw, scoresT, xbf, xsbf);
    k_gemm1<<<(T_TOK / 256) * (NN2 / 128), 512, 0, stream>>>(xbf, xsbf, sgw, suw, gup, h2);
    k_gemm2<<<256, 512, 0, stream>>>(h2, sdw, dwn, out);
}

// Round 13
// 213.087 us; speedup vs baseline: 1.1719x; 1.1719x over previous
//
#include <hip/hip_runtime.h>
#include <hip/hip_bf16.h>
#include <stdint.h>

#define T_TOK 2048
#define HD    1024
#define ID    4096
#define NE    8
#define NN2   8192   // 2*ID
#define CHUNK 256    // T_TOK / NE

typedef short          bf16x8 __attribute__((ext_vector_type(8)));
typedef float          f32x4  __attribute__((ext_vector_type(4)));
typedef unsigned short u16;

__device__ __forceinline__ u16 f2bf(float f) {
    return __builtin_bit_cast(u16, __float2bfloat16(f));
}

// Barrier that does NOT drain vmcnt: LDS-ordering only (T3/T4 pattern).
__device__ __forceinline__ void lgkm_bar() {
    asm volatile("s_waitcnt lgkmcnt(0)" ::: "memory");
    __builtin_amdgcn_s_barrier();
}

template<bool NT>
__device__ __forceinline__ float ldf(const float* p) {
    if constexpr (NT) return __builtin_nontemporal_load(p);
    else              return *p;
}

// ---------------------------------------------------------------- router ----
__global__ __launch_bounds__(256) void k_router(
    const float* __restrict__ x, const float* __restrict__ rw,
    float* __restrict__ scoresT, u16* __restrict__ xbf, u16* __restrict__ xsbf)
{
    const int t   = blockIdx.x;
    const int tid = threadIdx.x;
    __shared__ float wred[NE][4];
    __shared__ float ssc;

    float4 xv = reinterpret_cast<const float4*>(x + (size_t)t * HD)[tid];
    float p[NE];
#pragma unroll
    for (int e = 0; e < NE; ++e) p[e] = 0.f;
    const float* wrow = rw + (size_t)tid * 4 * NE;
    float xj[4] = {xv.x, xv.y, xv.z, xv.w};
#pragma unroll
    for (int j = 0; j < 4; ++j)
#pragma unroll
        for (int e = 0; e < NE; ++e) p[e] += xj[j] * wrow[j * NE + e];

#pragma unroll
    for (int e = 0; e < NE; ++e) {
        float v = p[e];
#pragma unroll
        for (int o = 32; o > 0; o >>= 1) v += __shfl_down(v, o, 64);
        if ((tid & 63) == 0) wred[e][tid >> 6] = v;
    }
    __syncthreads();
    if (tid == 0) {
        float mx = -3.4e38f; int am = 0;
        float lg[NE];
#pragma unroll
        for (int e = 0; e < NE; ++e) {
            lg[e] = wred[e][0] + wred[e][1] + wred[e][2] + wred[e][3];
            if (lg[e] > mx) { mx = lg[e]; am = e; }
        }
        float sc = 1.f / (1.f + __expf(-mx));
        ssc = sc;
#pragma unroll
        for (int e = 0; e < NE; ++e)
            scoresT[(size_t)e * T_TOK + t] = (e == am) ? sc : 0.f;
    }
    __syncthreads();
    const float sc = ssc;
    ushort4 a, b;
    a.x = f2bf(xj[0]); a.y = f2bf(xj[1]); a.z = f2bf(xj[2]); a.w = f2bf(xj[3]);
    b.x = f2bf(xj[0] * sc); b.y = f2bf(xj[1] * sc); b.z = f2bf(xj[2] * sc); b.w = f2bf(xj[3] * sc);
    reinterpret_cast<ushort4*>(xbf  + (size_t)t * HD)[tid] = a;
    reinterpret_cast<ushort4*>(xsbf + (size_t)t * HD)[tid] = b;
}

// ------------------------------------------------------------------- G1 -----
// r10 pipeline (110 us), split into two template instantiations:
//   EXPERT=0 (shared half, nt<32): sgw/suw CACHED loads (4 MB/XCD slab ->
//     L2/L3-served across the 8 co-resident mt blocks; nt was evicting it).
//   EXPERT=1 (expert half): gup NON-TEMPORAL (stream-once compulsory HBM).
// BM=256, BN=128, BK=32, 8 waves (4x2), dual-bank A direct from global,
// depth-2 B reg-staged into dbuf LDS, lgkm-only barriers.
template<bool EXPERT>
__global__ __launch_bounds__(512, 2) void k_gemm1(
    const u16* __restrict__ xbf, const u16* __restrict__ xsbf,
    const float* __restrict__ sgw, const float* __restrict__ suw,
    const float* __restrict__ gup, u16* __restrict__ h2)
{
    constexpr int BM = 256, BN = 128, BK = 32, NS = HD / BK;   // 32 steps
    const int d = blockIdx.x;                                  // 256 blocks/half
    int mt, nt;
    const u16* A; const float* Bg; const float* Bu; int ldb;
    if constexpr (!EXPERT) {
        const int r = d & 7, q = d >> 3;
        nt = r + 8 * (q & 3); mt = q >> 2;          // nt 0..31, same-nt per XCD
        A = xbf; Bg = sgw + nt * BN; Bu = suw + nt * BN; ldb = ID;
    } else {
        mt = d & 7; nt = 32 + (d >> 3);             // mt = XCD pin
        A = xsbf;
        Bg = gup + (size_t)mt * HD * NN2 + (nt * BN - ID);
        Bu = Bg + ID;
        ldb = NN2;
    }
    const int m0 = mt * BM, n0 = nt * BN;

    __shared__ u16 Bgs[2][BN * BK];
    __shared__ u16 Bus[2][BN * BK];

    const int tid  = threadIdx.x;
    const int lane = tid & 63, wid = tid >> 6;
    const int wr = wid >> 1, wc = wid & 1;        // 4 x 2 wave grid
    const int lrow = lane & 15, kg = lane >> 4;

    f32x4 accg[4][4], accu[4][4];
#pragma unroll
    for (int i = 0; i < 4; ++i)
#pragma unroll
        for (int j = 0; j < 4; ++j)
#pragma unroll
            for (int r = 0; r < 4; ++r) { accg[i][j][r] = 0.f; accu[i][j][r] = 0.f; }

    const int bcol = tid & 127, bkh = tid >> 7;   // B: 128 cols x 4 k-octets
    const int bsw  = (bcol >> 1) & 3;
    const u16* aBase = A + (size_t)(m0 + wr * 64 + lrow) * HD + kg * 8;

    float g0[8], u0[8], g1[8], u1[8];
    bf16x8 aF0[4], aF1[4];

#define LOADB(ks, rg, ru) do {                                                  \
        const float* bgp_ = Bg + (size_t)((ks) * BK + bkh * 8) * ldb + bcol;    \
        const float* bup_ = Bu + (size_t)((ks) * BK + bkh * 8) * ldb + bcol;    \
        _Pragma("unroll")                                                       \
        for (int j = 0; j < 8; ++j) {                                           \
            rg[j] = ldf<EXPERT>(bgp_ + (size_t)j * ldb);                        \
            ru[j] = ldf<EXPERT>(bup_ + (size_t)j * ldb);                        \
        }                                                                       \
    } while (0)

#define STOREB(b, rg, ru) do {                                                  \
        bf16x8 wg_, wu_;                                                        \
        _Pragma("unroll")                                                       \
        for (int j = 0; j < 8; ++j) { wg_[j] = (short)f2bf(rg[j]);              \
                                      wu_[j] = (short)f2bf(ru[j]); }            \
        *reinterpret_cast<bf16x8*>(reinterpret_cast<char*>(Bgs[b])              \
            + bcol * 64 + ((bkh ^ bsw) * 16)) = wg_;                            \
        *reinterpret_cast<bf16x8*>(reinterpret_cast<char*>(Bus[b])              \
            + bcol * 64 + ((bkh ^ bsw) * 16)) = wu_;                            \
    } while (0)

#define LOADA(ks, F) do {                                                       \
        _Pragma("unroll")                                                       \
        for (int mf = 0; mf < 4; ++mf)                                          \
            F[mf] = *reinterpret_cast<const bf16x8*>(                           \
                aBase + (size_t)mf * 16 * HD + (ks) * BK);                      \
    } while (0)

#define MFMAPH(b, F) do {                                                       \
        const char* gs_ = (const char*)Bgs[b];                                  \
        const char* us_ = (const char*)Bus[b];                                  \
        bf16x8 bgf_[4], buf_[4];                                                \
        _Pragma("unroll")                                                       \
        for (int nf = 0; nf < 4; ++nf) {                                        \
            const int col_ = wc * 64 + nf * 16 + lrow;                          \
            const int so_  = col_ * 64 + ((kg ^ ((col_ >> 1) & 3)) * 16);       \
            bgf_[nf] = *reinterpret_cast<const bf16x8*>(gs_ + so_);             \
            buf_[nf] = *reinterpret_cast<const bf16x8*>(us_ + so_);             \
        }                                                                       \
        _Pragma("unroll")                                                       \
        for (int mf = 0; mf < 4; ++mf)                                          \
            _Pragma("unroll")                                                   \
            for (int nf = 0; nf < 4; ++nf) {                                    \
                accg[mf][nf] = __builtin_amdgcn_mfma_f32_16x16x32_bf16(         \
                    F[mf], bgf_[nf], accg[mf][nf], 0, 0, 0);                    \
                accu[mf][nf] = __builtin_amdgcn_mfma_f32_16x16x32_bf16(         \
                    F[mf], buf_[nf], accu[mf][nf], 0, 0, 0);                    \
            }                                                                   \
    } while (0)

    // prologue
    LOADB(0, g0, u0);
    LOADB(1, g1, u1);
    LOADA(0, aF0);
    STOREB(0, g0, u0);
    lgkm_bar();

    for (int j = 0; j < NS / 2; ++j) {
        const int ks = 2 * j;
        // even step: compute tile ks (LDS buf0, aF0)
        {
            const int ka = (ks + 1 < NS) ? ks + 1 : NS - 1;
            const int kb = (ks + 2 < NS) ? ks + 2 : NS - 1;
            LOADA(ka, aF1);
            LOADB(kb, g0, u0);
        }
        MFMAPH(0, aF0);
        STOREB(1, g1, u1);
        lgkm_bar();
        // odd step: compute tile ks+1 (LDS buf1, aF1)
        {
            const int ka = (ks + 2 < NS) ? ks + 2 : NS - 1;
            const int kb = (ks + 3 < NS) ? ks + 3 : NS - 1;
            LOADA(ka, aF0);
            LOADB(kb, g1, u1);
        }
        MFMAPH(1, aF1);
        STOREB(0, g0, u0);
        lgkm_bar();
    }
#undef LOADB
#undef STOREB
#undef LOADA
#undef MFMAPH

    // SwiGLU epilogue -> bf16 H2
#pragma unroll
    for (int mf = 0; mf < 4; ++mf)
#pragma unroll
        for (int nf = 0; nf < 4; ++nf) {
            const int col = n0 + wc * 64 + nf * 16 + lrow;
#pragma unroll
            for (int r = 0; r < 4; ++r) {
                const int row = m0 + wr * 64 + mf * 16 + kg * 4 + r;
                const float g = accg[mf][nf][r];
                const float u = accu[mf][nf][r];
                const float h = (g / (1.f + __expf(-g))) * u;
                h2[(size_t)row * NN2 + col] = f2bf(h);
            }
        }
}

// ------------------------------------------------------------------- G2 -----
// UNCHANGED round-11 configuration (~92 us): BM=256, BN=64, K split across
// blocks (kh=0 sdw / kh=1 dwn[mt]); mt = XCD (h2 slab L2-hot); 2 wavesets x
// 4 waves over K-quarters; depth-2 B, dual-bank A, lgkm barriers; LDS
// waveset-reduce; kh-partials atomicAdd'ed onto zeroed out.
__global__ __launch_bounds__(512, 1) void k_gemm2(
    const u16* __restrict__ h2, const float* __restrict__ sdw,
    const float* __restrict__ dwn, float* __restrict__ out)
{
    constexpr int BM = 256, BN = 64, BK = 64, NS = 2048 / BK;  // 32 steps/waveset
    const int d   = blockIdx.x;               // 256 blocks
    const int mt  = d & 7;                    // = XCD
    const int q   = d >> 3;
    const int kh  = q & 1;                    // K-half: 0=sdw, 1=dwn[mt]
    const int nt  = q >> 1;                   // 0..15
    const int m0 = mt * BM, n0 = nt * BN;

    const int tid = threadIdx.x;
    const int ws  = tid >> 8;                 // waveset 0/1
    const int wt  = tid & 255;
    const int lane = wt & 63, wid4 = wt >> 6;
    const int wr = wid4;                      // 4x1 wave grid
    const int lrow = lane & 15, kg = lane >> 4;

    __shared__ char smem[65536];
    u16*   BsBase = (u16*)smem;
    float* red    = (float*)smem;

    f32x4 acc[4][4];
#pragma unroll
    for (int i = 0; i < 4; ++i)
#pragma unroll
        for (int j = 0; j < 4; ++j)
#pragma unroll
            for (int r = 0; r < 4; ++r) acc[i][j][r] = 0.f;

    const float* Bbase = kh ? (dwn + (size_t)mt * ID * HD + (size_t)(ws * 2048) * HD)
                            : (sdw + (size_t)(ws * 2048) * HD);
    const u16* aBase = h2 + (size_t)(m0 + wr * 64 + lrow) * NN2
                          + (size_t)kh * ID + (size_t)ws * 2048 + kg * 8;

    const int bcol = wt & 63, bkq = wt >> 6;
    const int bsw  = bcol & 7;

    float rb0[16], rb1[16];
    bf16x8 aF0[8], aF1[8];

#define LOADB2(ks, rb) do {                                                     \
        const float* bb_ = Bbase + (size_t)((ks) * BK + bkq * 16) * HD + n0 + bcol; \
        _Pragma("unroll")                                                       \
        for (int j = 0; j < 16; ++j) rb[j] = bb_[(size_t)j * HD];               \
    } while (0)

#define STOREB2(b, rb) do {                                                     \
        bf16x8 w0_, w1_;                                                        \
        _Pragma("unroll")                                                       \
        for (int j = 0; j < 8; ++j) { w0_[j] = (short)f2bf(rb[j]);              \
                                      w1_[j] = (short)f2bf(rb[8 + j]); }        \
        char* bs_ = (char*)(BsBase + (size_t)(ws * 2 + (b)) * BN * BK);         \
        *reinterpret_cast<bf16x8*>(bs_ + bcol * 128 + (((bkq * 2 + 0) ^ bsw) * 16)) = w0_; \
        *reinterpret_cast<bf16x8*>(bs_ + bcol * 128 + (((bkq * 2 + 1) ^ bsw) * 16)) = w1_; \
    } while (0)

#define LOADA2(ks, F) do {                                                      \
        _Pragma("unroll")                                                       \
        for (int mf = 0; mf < 4; ++mf)                                          \
            _Pragma("unroll")                                                   \
            for (int kk = 0; kk < 2; ++kk)                                      \
                F[mf * 2 + kk] = *reinterpret_cast<const bf16x8*>(              \
                    aBase + (size_t)mf * 16 * NN2 + (ks) * BK + kk * 32);       \
    } while (0)

#define MFMAPH2(b, F) do {                                                      \
        const char* bs_ = (const char*)(BsBase + (size_t)(ws * 2 + (b)) * BN * BK); \
        _Pragma("unroll")                                                       \
        for (int kk = 0; kk < 2; ++kk) {                                        \
            bf16x8 bf_[4];                                                      \
            _Pragma("unroll")                                                   \
            for (int nf = 0; nf < 4; ++nf) {                                    \
                const int col_ = nf * 16 + lrow;                                \
                bf_[nf] = *reinterpret_cast<const bf16x8*>(                     \
                    bs_ + col_ * 128 + (((kk * 4 + kg) ^ (col_ & 7)) * 16));    \
            }                                                                   \
            _Pragma("unroll")                                                   \
            for (int mf = 0; mf < 4; ++mf)                                      \
                _Pragma("unroll")                                               \
                for (int nf = 0; nf < 4; ++nf)                                  \
                    acc[mf][nf] = __builtin_amdgcn_mfma_f32_16x16x32_bf16(      \
                        F[mf * 2 + kk], bf_[nf], acc[mf][nf], 0, 0, 0);         \
        }                                                                       \
    } while (0)

    // prologue
    LOADB2(0, rb0);
    LOADB2(1, rb1);
    LOADA2(0, aF0);
    STOREB2(0, rb0);
    lgkm_bar();

    for (int j = 0; j < NS / 2; ++j) {
        const int ks = 2 * j;
        {
            const int ka = (ks + 1 < NS) ? ks + 1 : NS - 1;
            const int kb = (ks + 2 < NS) ? ks + 2 : NS - 1;
            LOADA2(ka, aF1);
            LOADB2(kb, rb0);
        }
        MFMAPH2(0, aF0);
        STOREB2(1, rb1);
        lgkm_bar();
        {
            const int ka = (ks + 2 < NS) ? ks + 2 : NS - 1;
            const int kb = (ks + 3 < NS) ? ks + 3 : NS - 1;
            LOADA2(ka, aF0);
            LOADB2(kb, rb1);
        }
        MFMAPH2(1, aF1);
        STOREB2(0, rb0);
        lgkm_bar();
    }
#undef LOADB2
#undef STOREB2
#undef LOADA2
#undef MFMAPH2

    // waveset reduce + atomic kh-combine
    lgkm_bar();
    if (ws == 1) {
#pragma unroll
        for (int mf = 0; mf < 4; ++mf)
#pragma unroll
            for (int nf = 0; nf < 4; ++nf)
#pragma unroll
                for (int r = 0; r < 4; ++r) {
                    const int row = wr * 64 + mf * 16 + kg * 4 + r;
                    const int col = nf * 16 + lrow;
                    red[row * 64 + col] = acc[mf][nf][r];
                }
    }
    lgkm_bar();
    if (ws == 0) {
#pragma unroll
        for (int mf = 0; mf < 4; ++mf)
#pragma unroll
            for (int nf = 0; nf < 4; ++nf)
#pragma unroll
                for (int r = 0; r < 4; ++r) {
                    const int row = wr * 64 + mf * 16 + kg * 4 + r;
                    const int col = nf * 16 + lrow;
                    atomicAdd(&out[(size_t)(m0 + row) * HD + n0 + col],
                              acc[mf][nf][r] + red[row * 64 + col]);
                }
    }
}

// --------------------------------------------------------------- launch -----
extern "C" void kernel_launch(void* const* d_in, const int* in_sizes, int n_in,
                              void* d_out, int out_size, void* d_ws, size_t ws_size,
                              hipStream_t stream) {
    const float* x   = (const float*)d_in[0];
    const float* rw  = (const float*)d_in[1];
    const float* gup = (const float*)d_in[2];
    const float* dwn = (const float*)d_in[3];
    const float* sgw = (const float*)d_in[4];
    const float* suw = (const float*)d_in[5];
    const float* sdw = (const float*)d_in[6];

    float* out     = (float*)d_out;
    float* scoresT = out + (size_t)T_TOK * HD;

    char* ws   = (char*)d_ws;
    u16* xbf   = (u16*)ws;                                    // 4 MB
    u16* xsbf  = (u16*)(ws + (size_t)T_TOK * HD * 2);         // 4 MB
    u16* h2    = (u16*)(ws + (size_t)2 * T_TOK * HD * 2);     // 32 MB

    // zero the final-output region: G2 accumulates kh-partials atomically
    hipMemsetAsync(out, 0, (size_t)T_TOK * HD * sizeof(float), stream);

    k_router<<<T_TOK, 256, 0, stream>>>(x, rw, scoresT, xbf, xsbf);
    k_gemm1<false><<<256, 512, 0, stream>>>(xbf, xsbf, sgw, suw, gup, h2);  // shared half, cached B
    k_gemm1<true ><<<256, 512, 0, stream>>>(xbf, xsbf, sgw, suw, gup, h2);  // expert half, nt B
    k_gemm2<<<256, 512, 0, stream>>>(h2, sdw, dwn, out);
}